// Round 1
// baseline (1907.775 us; speedup 1.0000x reference)
//
#include <hip/hip_runtime.h>

#define NNODES 100000
#define NEDGES 1600000
#define FIN 128
#define FHID 128
#define FOUT 64

// ---------------- graph preprocessing ----------------

__global__ __launch_bounds__(256) void zero3_kernel(int* a, int* b, int* c, int n) {
  int i = blockIdx.x * 256 + threadIdx.x;
  if (i < n) { a[i] = 0; b[i] = 0; c[i] = 0; }
}

__global__ __launch_bounds__(256) void degree_kernel(const int* __restrict__ src,
                                                     const int* __restrict__ dst,
                                                     int* __restrict__ deg_src,
                                                     int* __restrict__ deg_dst, int E) {
  int e = blockIdx.x * 256 + threadIdx.x;
  if (e < E) {
    atomicAdd(&deg_src[src[e]], 1);
    atomicAdd(&deg_dst[dst[e]], 1);
  }
}

__global__ __launch_bounds__(256) void norm_kernel(const int* __restrict__ deg_src,
                                                   const int* __restrict__ deg_dst,
                                                   float* __restrict__ norm_src,
                                                   float* __restrict__ norm_dst, int n) {
  int i = blockIdx.x * 256 + threadIdx.x;
  if (i < n) {
    norm_src[i] = rsqrtf(fmaxf((float)deg_src[i], 1.0f));
    norm_dst[i] = rsqrtf(fmaxf((float)deg_dst[i], 1.0f));
  }
}

__global__ __launch_bounds__(256) void scan_block_kernel(const int* __restrict__ deg,
                                                         int* __restrict__ offs,
                                                         int* __restrict__ bsums, int n) {
  __shared__ int sh[256];
  int i = blockIdx.x * 256 + threadIdx.x;
  int v = (i < n) ? deg[i] : 0;
  sh[threadIdx.x] = v;
  __syncthreads();
  for (int d = 1; d < 256; d <<= 1) {
    int t = (threadIdx.x >= d) ? sh[threadIdx.x - d] : 0;
    __syncthreads();
    sh[threadIdx.x] += t;
    __syncthreads();
  }
  if (i < n) offs[i] = sh[threadIdx.x] - v;  // exclusive
  if (threadIdx.x == 255) bsums[blockIdx.x] = sh[255];
}

__global__ void scan_sums_kernel(int* bsums, int nb) {
  if (threadIdx.x == 0 && blockIdx.x == 0) {
    int run = 0;
    for (int b = 0; b < nb; b++) { int t = bsums[b]; bsums[b] = run; run += t; }
  }
}

__global__ __launch_bounds__(256) void scan_add_kernel(int* __restrict__ offs,
                                                       const int* __restrict__ bsums, int n) {
  int i = blockIdx.x * 256 + threadIdx.x;
  if (i < n) offs[i] += bsums[blockIdx.x];
}

__global__ __launch_bounds__(256) void csr_fill_kernel(const int* __restrict__ src,
                                                       const int* __restrict__ dst,
                                                       const int* __restrict__ offs,
                                                       int* __restrict__ cursor,
                                                       int* __restrict__ csr, int E) {
  int e = blockIdx.x * 256 + threadIdx.x;
  if (e < E) {
    int d = dst[e];
    int pos = atomicAdd(&cursor[d], 1);
    csr[offs[d] + pos] = src[e];
  }
}

// ---------------- GEMM: Y[n,c] = norm[n] * sum_k X[n,k] * W[k,c] ----------------
// Tile 64 rows x 64 cols, K=128 entirely in LDS. Xs(32KB)+Ws(32KB)=64KB -> 2 blocks/CU.
// Thread = 4 rows x 4 cols register block.

template <int CTOT>
__global__ __launch_bounds__(256) void gemm_scale(const float* __restrict__ X,
                                                  const float* __restrict__ W,
                                                  const float* __restrict__ norm,
                                                  float* __restrict__ Y, int nrows) {
  constexpr int K = 128;
  constexpr int ROWS = 64;
  constexpr int CTILE = 64;
  __shared__ float Xs[ROWS][K];    // 32 KB
  __shared__ float Ws[K][CTILE];   // 32 KB
  const int tid = threadIdx.x;
  const int row0 = blockIdx.x * ROWS;
  const int col0 = blockIdx.y * CTILE;

  // stage W tile (K x CTILE), float4
  for (int i = tid; i < K * CTILE / 4; i += 256) {
    int k = i / (CTILE / 4);
    int c4 = (i % (CTILE / 4)) * 4;
    *(float4*)&Ws[k][c4] = *(const float4*)&W[(size_t)k * CTOT + col0 + c4];
  }
  // stage X tile (ROWS x K), float4, coalesced
  for (int i = tid; i < ROWS * K / 4; i += 256) {
    int r = i / (K / 4);
    int k4 = (i % (K / 4)) * 4;
    int gr = row0 + r;
    float4 v = make_float4(0.f, 0.f, 0.f, 0.f);
    if (gr < nrows) v = *(const float4*)&X[(size_t)gr * K + k4];
    *(float4*)&Xs[r][k4] = v;
  }
  __syncthreads();

  const int c0 = (tid & 15) * 4;
  const int r0 = (tid >> 4) * 4;
  float acc[4][4] = {};

#pragma unroll 8
  for (int k = 0; k < K; k++) {
    float4 wv = *(const float4*)&Ws[k][c0];
#pragma unroll
    for (int r = 0; r < 4; r++) {
      float xv = Xs[r0 + r][k];
      acc[r][0] = fmaf(xv, wv.x, acc[r][0]);
      acc[r][1] = fmaf(xv, wv.y, acc[r][1]);
      acc[r][2] = fmaf(xv, wv.z, acc[r][2]);
      acc[r][3] = fmaf(xv, wv.w, acc[r][3]);
    }
  }

#pragma unroll
  for (int r = 0; r < 4; r++) {
    int gr = row0 + r0 + r;
    if (gr < nrows) {
      float s = norm[gr];
      float4 o = make_float4(acc[r][0] * s, acc[r][1] * s, acc[r][2] * s, acc[r][3] * s);
      *(float4*)&Y[(size_t)gr * CTOT + col0 + c0] = o;
    }
  }
}

// ---------------- SpMM: Y[n,:] = relu?( (sum_{e: dst=n} H[src[e],:]) * norm_dst[n] + b ) ----

template <int F, bool RELU>
__global__ __launch_bounds__(256) void spmm_kernel(const float* __restrict__ H,
                                                   const int* __restrict__ offs,
                                                   const int* __restrict__ deg,
                                                   const int* __restrict__ csr,
                                                   const float* __restrict__ norm_dst,
                                                   const float* __restrict__ bias,
                                                   float* __restrict__ Y, int n) {
  constexpr int TPN = F / 4;        // threads per node (float4 lanes)
  constexpr int NPB = 256 / TPN;    // nodes per block
  int node = blockIdx.x * NPB + threadIdx.x / TPN;
  if (node >= n) return;
  int f4 = (threadIdx.x % TPN) * 4;
  int beg = offs[node];
  int end = beg + deg[node];
  float4 acc = make_float4(0.f, 0.f, 0.f, 0.f);
  for (int e = beg; e < end; e++) {
    int s = csr[e];
    const float4 h = *(const float4*)&H[(size_t)s * F + f4];
    acc.x += h.x; acc.y += h.y; acc.z += h.z; acc.w += h.w;
  }
  float nd = norm_dst[node];
  float4 bv = *(const float4*)&bias[f4];
  float4 o = make_float4(fmaf(acc.x, nd, bv.x), fmaf(acc.y, nd, bv.y),
                         fmaf(acc.z, nd, bv.z), fmaf(acc.w, nd, bv.w));
  if (RELU) {
    o.x = fmaxf(o.x, 0.f); o.y = fmaxf(o.y, 0.f);
    o.z = fmaxf(o.z, 0.f); o.w = fmaxf(o.w, 0.f);
  }
  *(float4*)&Y[(size_t)node * F + f4] = o;
}

// ---------------- driver ----------------

extern "C" void kernel_launch(void* const* d_in, const int* in_sizes, int n_in,
                              void* d_out, int out_size, void* d_ws, size_t ws_size,
                              hipStream_t stream) {
  const int N = NNODES;
  const int E = NEDGES;
  const float* W1 = (const float*)d_in[9];
  const float* b1 = (const float*)d_in[10];
  const float* W2 = (const float*)d_in[11];
  const float* b2 = (const float*)d_in[12];

  char* ws = (char*)d_ws;
  size_t off = 0;
  auto alloc = [&](size_t bytes) -> void* {
    void* p = ws + off;
    off += (bytes + 255) & ~(size_t)255;
    return p;
  };
  int* deg_src = (int*)alloc((size_t)N * 4);
  int* deg_dst = (int*)alloc((size_t)N * 4);
  float* norm_src = (float*)alloc((size_t)N * 4);
  float* norm_dst = (float*)alloc((size_t)N * 4);
  int* offs = (int*)alloc((size_t)N * 4);
  int* cursor = (int*)alloc((size_t)N * 4);
  int* bsums = (int*)alloc(512 * 4);
  int* csr = (int*)alloc((size_t)E * 4);
  float* H = (float*)alloc((size_t)N * FHID * 4);  // gemm output (also reused for layer2)
  float* T = (float*)alloc((size_t)N * FHID * 4);  // layer-1 output

  const int nb = (N + 255) / 256;       // 391
  const int eb = (E + 255) / 256;       // 6250
  const int gemm_rb = (N + 63) / 64;    // 1563

  for (int g = 0; g < 3; g++) {
    const float* feat = (const float*)d_in[3 * g + 0];
    const int* src = (const int*)d_in[3 * g + 1];
    const int* dst = (const int*)d_in[3 * g + 2];
    float* zout = (float*)d_out + (size_t)g * N * FOUT;

    // preprocessing: degrees, norms, CSR-by-dst
    zero3_kernel<<<nb, 256, 0, stream>>>(deg_src, deg_dst, cursor, N);
    degree_kernel<<<eb, 256, 0, stream>>>(src, dst, deg_src, deg_dst, E);
    norm_kernel<<<nb, 256, 0, stream>>>(deg_src, deg_dst, norm_src, norm_dst, N);
    scan_block_kernel<<<nb, 256, 0, stream>>>(deg_dst, offs, bsums, N);
    scan_sums_kernel<<<1, 64, 0, stream>>>(bsums, nb);
    scan_add_kernel<<<nb, 256, 0, stream>>>(offs, bsums, N);
    csr_fill_kernel<<<eb, 256, 0, stream>>>(src, dst, offs, cursor, csr, E);

    // layer 1: H = (feat @ W1) * norm_src ; T = relu(spmm(H) * norm_dst + b1)
    gemm_scale<FHID><<<dim3(gemm_rb, FHID / 64), 256, 0, stream>>>(feat, W1, norm_src, H, N);
    {
      constexpr int NPB = 256 / (FHID / 4);  // 8 nodes/block
      spmm_kernel<FHID, true><<<(N + NPB - 1) / NPB, 256, 0, stream>>>(
          H, offs, deg_dst, csr, norm_dst, b1, T, N);
    }

    // layer 2: H = (T @ W2) * norm_src ; z = spmm(H) * norm_dst + b2
    gemm_scale<FOUT><<<dim3(gemm_rb, FOUT / 64), 256, 0, stream>>>(T, W2, norm_src, H, N);
    {
      constexpr int NPB = 256 / (FOUT / 4);  // 16 nodes/block
      spmm_kernel<FOUT, false><<<(N + NPB - 1) / NPB, 256, 0, stream>>>(
          H, offs, deg_dst, csr, norm_dst, b2, zout, N);
    }
  }
}